// Round 1
// baseline (136.729 us; speedup 1.0000x reference)
//
#include <hip/hip_runtime.h>

static constexpr int NN  = 4194304;   // N
static constexpr int NB  = 4096;      // blocks; NB * TPB * 4 rows == NN
static constexpr int TPB = 256;

// ---------------------------------------------------------------------------
// R5: R4-best + non-temporal loads on the zero-reuse streams (pp, pa, ta).
// Theory: 96 MB/iter streams through L2 (32 MB) with no reuse; if the
// ~2.4-3.2 TB/s read ceiling is partly L2-path pollution/contention, the nt
// cache policy should lift it. tp stays default-cached: the tp[i-1]/tp[i+4]
// scalar neighbor loads rely on L1/L2 hits against adjacent lanes' float4s.
// Everything else is identical to the R4-best kernel (schedule-insensitive
// per R4-R7; fences/atomics ruled out in R3).
// ---------------------------------------------------------------------------

typedef float f4v __attribute__((ext_vector_type(4)));
typedef int   i4v __attribute__((ext_vector_type(4)));

__global__ __launch_bounds__(256) void pfl_main(
    const float* __restrict__ pp,   // pred_prices [N]
    const float* __restrict__ pa,   // pred_actions [N,3]
    const float* __restrict__ tp,   // tgt_prices [N]
    const int*   __restrict__ ta,   // tgt_actions [N] (int32)
    float* __restrict__ bsum)       // [3*NB] per-block partials
{
    const int tid = threadIdx.x;
    const int bid = blockIdx.x;
    const int g   = bid * TPB + tid;   // group of 4 rows
    const int i   = g * 4;

    const f4v* pp4 = (const f4v*)pp;
    const float4* tp4 = (const float4*)tp;
    const f4v* pa4 = (const f4v*)pa;
    const i4v* ta4 = (const i4v*)ta;

    // ---- loads (all issued up front) -----------------------------------
    // nt on the no-reuse streams; tp stays cached for the neighbor scalars.
    f4v    p  = __builtin_nontemporal_load(pp4 + g);
    float4 t  = tp4[g];
    i4v    a  = __builtin_nontemporal_load(ta4 + g);
    f4v    A0 = __builtin_nontemporal_load(pa4 + 3*g + 0);
    f4v    A1 = __builtin_nontemporal_load(pa4 + 3*g + 1);
    f4v    A2 = __builtin_nontemporal_load(pa4 + 3*g + 2);
    float tm1 = (i > 0)      ? tp[i - 1] : 0.f;   // L1 hits
    float tnx = (i + 4 < NN) ? tp[i + 4] : 0.f;

    float tv[6] = {tm1, t.x, t.y, t.z, t.w, tnx};
    float pv[4] = {p.x, p.y, p.z, p.w};
    float rows[4][3] = {{A0.x, A0.y, A0.z},
                        {A0.w, A1.x, A1.y},
                        {A1.z, A1.w, A2.x},
                        {A2.y, A2.z, A2.w}};
    int av[4] = {a.x, a.y, a.z, a.w};

    float sq = 0.f, ce = 0.f, pw = 0.f;

    #pragma unroll
    for (int j = 0; j < 4; ++j) {
        const int idx = i + j;
        // MSE
        float d = pv[j] - tv[j + 1];
        sq += d * d;

        // cross-entropy via logsumexp over 3 logits
        float x0 = rows[j][0], x1 = rows[j][1], x2 = rows[j][2];
        float m  = fmaxf(x0, fmaxf(x1, x2));
        float lse = m + __logf(__expf(x0 - m) + __expf(x1 - m) + __expf(x2 - m));
        float tgt = (av[j] == 0) ? x0 : ((av[j] == 1) ? x1 : x2);
        ce += lse - tgt;

        // argmax (first-max, matches jnp.argmax)
        int pidx = 0;
        float best = x0;
        if (x1 > best) { best = x1; pidx = 1; }
        if (x2 > best) { pidx = 2; }

        float profit = 0.f;
        if (pidx == 0)      profit = (idx + 1 < NN) ? (tv[j + 2] - tv[j + 1]) : 0.f;
        else if (pidx == 2) profit = (idx > 0)      ? (tv[j + 1] - tv[j])     : 0.f;

        pw += 1.f / (1.f + __expf(-10.f * profit));
    }

    // ---- block reduction (wave-64 shuffle -> LDS) ----------------------
    #pragma unroll
    for (int off = 32; off > 0; off >>= 1) {
        sq += __shfl_down(sq, off, 64);
        ce += __shfl_down(ce, off, 64);
        pw += __shfl_down(pw, off, 64);
    }

    __shared__ float s_sq[4], s_ce[4], s_pw[4];
    const int lane = tid & 63;
    const int wid  = tid >> 6;
    if (lane == 0) { s_sq[wid] = sq; s_ce[wid] = ce; s_pw[wid] = pw; }
    __syncthreads();

    if (tid == 0) {
        bsum[bid]          = s_sq[0] + s_sq[1] + s_sq[2] + s_sq[3];
        bsum[NB + bid]     = s_ce[0] + s_ce[1] + s_ce[2] + s_ce[3];
        bsum[2 * NB + bid] = s_pw[0] + s_pw[1] + s_pw[2] + s_pw[3];
    }
}

// ---------------------------------------------------------------------------
// Finalize: 1024 threads, float4 loads — each thread grabs one float4 from
// each of the three partial arrays (4096 floats = 1024 float4 each).
// out = 0.7 * (ce/N) * (pw/N) + 0.3 * (sq/N)
// ---------------------------------------------------------------------------
__global__ __launch_bounds__(1024) void pfl_final(const float* __restrict__ bsum,
                                                  float* __restrict__ out) {
    const int tid = threadIdx.x;
    const float4* b4 = (const float4*)bsum;
    const int Q = NB / 4;               // 1024 float4 per array

    float4 vsq = b4[tid];               // array 0: [0,   Q)
    float4 vce = b4[Q + tid];           // array 1: [Q,  2Q)
    float4 vpw = b4[2 * Q + tid];       // array 2: [2Q, 3Q)

    double sq = (double)vsq.x + vsq.y + vsq.z + vsq.w;
    double ce = (double)vce.x + vce.y + vce.z + vce.w;
    double pw = (double)vpw.x + vpw.y + vpw.z + vpw.w;

    #pragma unroll
    for (int off = 32; off > 0; off >>= 1) {
        sq += __shfl_down(sq, off, 64);
        ce += __shfl_down(ce, off, 64);
        pw += __shfl_down(pw, off, 64);
    }

    __shared__ double s_sq[16], s_ce[16], s_pw[16];
    const int lane = tid & 63;
    const int wid  = tid >> 6;
    if (lane == 0) { s_sq[wid] = sq; s_ce[wid] = ce; s_pw[wid] = pw; }
    __syncthreads();

    if (tid == 0) {
        double tsq = 0.0, tce = 0.0, tpw = 0.0;
        #pragma unroll
        for (int w = 0; w < 16; ++w) { tsq += s_sq[w]; tce += s_ce[w]; tpw += s_pw[w]; }
        const double inv = 1.0 / (double)NN;
        out[0] = (float)(0.7 * (tce * inv) * (tpw * inv) + 0.3 * (tsq * inv));
    }
}

extern "C" void kernel_launch(void* const* d_in, const int* in_sizes, int n_in,
                              void* d_out, int out_size, void* d_ws, size_t ws_size,
                              hipStream_t stream) {
    const float* pp = (const float*)d_in[0];   // pred_prices
    const float* pa = (const float*)d_in[1];   // pred_actions [N,3]
    const float* tp = (const float*)d_in[2];   // tgt_prices
    const int*   ta = (const int*)d_in[3];     // tgt_actions (int32)
    // d_in[4] (prices) unused by reference.

    float* bsum = (float*)d_ws;                // 3*NB floats = 48 KB (written, not RMW)

    pfl_main<<<NB, TPB, 0, stream>>>(pp, pa, tp, ta, bsum);
    pfl_final<<<1, 1024, 0, stream>>>(bsum, (float*)d_out);
}

// Round 2
// 134.446 us; speedup vs baseline: 1.0170x; 1.0170x over previous
//
#include <hip/hip_runtime.h>

static constexpr int NN  = 4194304;   // N
static constexpr int NB  = 4096;      // blocks; NB * TPB * 4 rows == NN
static constexpr int TPB = 256;

// ---------------------------------------------------------------------------
// R6: stage ALL input streams via global_load_lds (DMA global->LDS, 16B/lane)
// instead of vector loads to VGPRs.
// Theory: the ~2.7 TB/s read ceiling (vs 6.6 TB/s write fills) matches a
// per-CU L1 outstanding-miss limit (~32 lines x 128B / 375ns x 256 CU =
// 2.8 TB/s). The LDS-DMA path skips the VGPR/L1 return and may not consume
// the same miss-tracking resources -> deeper pipeline of outstanding reads.
// nt cache policy (R5) was null; schedule (R4-R7) was null; this is the one
// untried read path.
// LDS layout is linear in lane order (wave-uniform base + lane*16, m104);
// pa is staged as 3 lane-contiguous 64-float4 chunks per wave.
// ---------------------------------------------------------------------------

#define GL2LDS(gp, lp)                                                         \
    __builtin_amdgcn_global_load_lds(                                          \
        (const __attribute__((address_space(1))) void*)(gp),                   \
        (__attribute__((address_space(3))) void*)(lp), 16, 0, 0)

__global__ __launch_bounds__(256) void pfl_main(
    const float* __restrict__ pp,   // pred_prices [N]
    const float* __restrict__ pa,   // pred_actions [N,3]
    const float* __restrict__ tp,   // tgt_prices [N]
    const int*   __restrict__ ta,   // tgt_actions [N] (int32)
    float* __restrict__ bsum)       // [3*NB] per-block partials
{
    const int tid  = threadIdx.x;
    const int bid  = blockIdx.x;
    const int g    = bid * TPB + tid;   // group of 4 rows
    const int i    = g * 4;
    const int wid  = tid >> 6;
    const int lane = tid & 63;

    __shared__ float s_pp[4 * TPB];     //  4 KB: block's 1024 pred_prices
    __shared__ float s_tp[4 * TPB];     //  4 KB: block's 1024 tgt_prices
    __shared__ int   s_ta[4 * TPB];     //  4 KB: block's 1024 tgt_actions
    __shared__ float s_pa[12 * TPB];    // 12 KB: block's 1024 rows x 3 logits

    // ---- DMA staging: 6 x global_load_lds dwordx4 per thread -----------
    {
        const float4* pp4 = (const float4*)pp;
        const float4* tp4 = (const float4*)tp;
        const int4*   ta4 = (const int4*)ta;
        const float4* pa4 = (const float4*)pa;

        GL2LDS(pp4 + g, &s_pp[tid * 4]);
        GL2LDS(tp4 + g, &s_tp[tid * 4]);
        GL2LDS(ta4 + g, &s_ta[tid * 4]);

        // pa: wave 'wid' owns float4 indices [3*bid*256 + wid*192, +192)
        const int base4 = 3 * (bid * TPB);
        #pragma unroll
        for (int c = 0; c < 3; ++c) {
            const int k = wid * 192 + c * 64 + lane;   // block-local float4 idx
            GL2LDS(pa4 + (base4 + k), &s_pa[k * 4]);
        }
    }

    // block-boundary neighbor scalars (2 global dword loads per BLOCK)
    float tm1_edge = 0.f, tnx_edge = 0.f;
    if (tid == 0       && i > 0)      tm1_edge = tp[i - 1];
    if (tid == TPB - 1 && i + 4 < NN) tnx_edge = tp[i + 4];

    asm volatile("s_waitcnt vmcnt(0)" ::: "memory");
    __syncthreads();

    // ---- compute from LDS ----------------------------------------------
    float4 p  = *(const float4*)&s_pp[tid * 4];
    float4 t  = *(const float4*)&s_tp[tid * 4];
    int4   a  = *(const int4*)&s_ta[tid * 4];
    float4 R0 = *(const float4*)&s_pa[tid * 12 + 0];
    float4 R1 = *(const float4*)&s_pa[tid * 12 + 4];
    float4 R2 = *(const float4*)&s_pa[tid * 12 + 8];

    const float tm1 = (tid == 0)       ? tm1_edge : s_tp[tid * 4 - 1];
    const float tnx = (tid == TPB - 1) ? tnx_edge : s_tp[tid * 4 + 4];

    float tv[6] = {tm1, t.x, t.y, t.z, t.w, tnx};
    float pv[4] = {p.x, p.y, p.z, p.w};
    float rows[4][3] = {{R0.x, R0.y, R0.z},
                        {R0.w, R1.x, R1.y},
                        {R1.z, R1.w, R2.x},
                        {R2.y, R2.z, R2.w}};
    int av[4] = {a.x, a.y, a.z, a.w};

    float sq = 0.f, ce = 0.f, pw = 0.f;

    #pragma unroll
    for (int j = 0; j < 4; ++j) {
        const int idx = i + j;
        // MSE
        float d = pv[j] - tv[j + 1];
        sq += d * d;

        // cross-entropy via logsumexp over 3 logits
        float x0 = rows[j][0], x1 = rows[j][1], x2 = rows[j][2];
        float m  = fmaxf(x0, fmaxf(x1, x2));
        float lse = m + __logf(__expf(x0 - m) + __expf(x1 - m) + __expf(x2 - m));
        float tgt = (av[j] == 0) ? x0 : ((av[j] == 1) ? x1 : x2);
        ce += lse - tgt;

        // argmax (first-max, matches jnp.argmax)
        int pidx = 0;
        float best = x0;
        if (x1 > best) { best = x1; pidx = 1; }
        if (x2 > best) { pidx = 2; }

        float profit = 0.f;
        if (pidx == 0)      profit = (idx + 1 < NN) ? (tv[j + 2] - tv[j + 1]) : 0.f;
        else if (pidx == 2) profit = (idx > 0)      ? (tv[j + 1] - tv[j])     : 0.f;

        pw += 1.f / (1.f + __expf(-10.f * profit));
    }

    // ---- block reduction (wave-64 shuffle -> LDS) ----------------------
    #pragma unroll
    for (int off = 32; off > 0; off >>= 1) {
        sq += __shfl_down(sq, off, 64);
        ce += __shfl_down(ce, off, 64);
        pw += __shfl_down(pw, off, 64);
    }

    __shared__ float s_sq[4], s_ce[4], s_pw[4];
    if (lane == 0) { s_sq[wid] = sq; s_ce[wid] = ce; s_pw[wid] = pw; }
    __syncthreads();

    if (tid == 0) {
        bsum[bid]          = s_sq[0] + s_sq[1] + s_sq[2] + s_sq[3];
        bsum[NB + bid]     = s_ce[0] + s_ce[1] + s_ce[2] + s_ce[3];
        bsum[2 * NB + bid] = s_pw[0] + s_pw[1] + s_pw[2] + s_pw[3];
    }
}

// ---------------------------------------------------------------------------
// Finalize: 1024 threads, float4 loads — each thread grabs one float4 from
// each of the three partial arrays (4096 floats = 1024 float4 each).
// out = 0.7 * (ce/N) * (pw/N) + 0.3 * (sq/N)
// ---------------------------------------------------------------------------
__global__ __launch_bounds__(1024) void pfl_final(const float* __restrict__ bsum,
                                                  float* __restrict__ out) {
    const int tid = threadIdx.x;
    const float4* b4 = (const float4*)bsum;
    const int Q = NB / 4;               // 1024 float4 per array

    float4 vsq = b4[tid];               // array 0: [0,   Q)
    float4 vce = b4[Q + tid];           // array 1: [Q,  2Q)
    float4 vpw = b4[2 * Q + tid];       // array 2: [2Q, 3Q)

    double sq = (double)vsq.x + vsq.y + vsq.z + vsq.w;
    double ce = (double)vce.x + vce.y + vce.z + vce.w;
    double pw = (double)vpw.x + vpw.y + vpw.z + vpw.w;

    #pragma unroll
    for (int off = 32; off > 0; off >>= 1) {
        sq += __shfl_down(sq, off, 64);
        ce += __shfl_down(ce, off, 64);
        pw += __shfl_down(pw, off, 64);
    }

    __shared__ double s_sq[16], s_ce[16], s_pw[16];
    const int lane = tid & 63;
    const int wid  = tid >> 6;
    if (lane == 0) { s_sq[wid] = sq; s_ce[wid] = ce; s_pw[wid] = pw; }
    __syncthreads();

    if (tid == 0) {
        double tsq = 0.0, tce = 0.0, tpw = 0.0;
        #pragma unroll
        for (int w = 0; w < 16; ++w) { tsq += s_sq[w]; tce += s_ce[w]; tpw += s_pw[w]; }
        const double inv = 1.0 / (double)NN;
        out[0] = (float)(0.7 * (tce * inv) * (tpw * inv) + 0.3 * (tsq * inv));
    }
}

extern "C" void kernel_launch(void* const* d_in, const int* in_sizes, int n_in,
                              void* d_out, int out_size, void* d_ws, size_t ws_size,
                              hipStream_t stream) {
    const float* pp = (const float*)d_in[0];   // pred_prices
    const float* pa = (const float*)d_in[1];   // pred_actions [N,3]
    const float* tp = (const float*)d_in[2];   // tgt_prices
    const int*   ta = (const int*)d_in[3];     // tgt_actions (int32)
    // d_in[4] (prices) unused by reference.

    float* bsum = (float*)d_ws;                // 3*NB floats = 48 KB (written, not RMW)

    pfl_main<<<NB, TPB, 0, stream>>>(pp, pa, tp, ta, bsum);
    pfl_final<<<1, 1024, 0, stream>>>(bsum, (float*)d_out);
}